// Round 1
// baseline (253.616 us; speedup 1.0000x reference)
//
#include <hip/hip_runtime.h>

// DeltaRule: T=8192 scan over B=4096 independent sequences.
// Diagonal-affine recurrence -> chunked parallel scan, 3 dispatches:
//   P1: per (chunk, seq) compose affine map (A0,B0,A1,B1); bit-pack x (x is exactly 0/1)
//   P2: parallel Kogge-Stone scan over the NCHUNK chunk-maps (one block per seq-group)
//   P3: replay each chunk from its exact start state using packed bits, emit preds
//
// R2 changes vs R1: CHUNK 64 -> 32.
//   - p1/p3 grids double (512 -> 1024 blocks): 16 waves/CU instead of 8, and the
//     per-thread sequential chain halves -> better BW saturation on the two
//     streaming kernels (the only compulsory traffic: 134 MB read + 134 MB write).
//   - bits fit one u32 per lane (uint4 per thread) -> p3 loses the hi/lo select.
//   - maps stored AoS-interleaved (4 x float4 = 64 B per (chunk,seqgroup)) so p2's
//     gather is one contiguous 64 B per thread instead of 4 lines 16 KiB apart.
//   - p2 generalized to 256 threads (4 waves): intra-wave shuffle scan + LDS
//     cross-wave combine. Intermediates total 28 MB (L2/L3-resident).

constexpr int T_LEN  = 8192;
constexpr int B_SEQ  = 4096;
constexpr int B4     = B_SEQ / 4;       // 1024 float4 seq-groups
constexpr int CHUNK  = 32;
constexpr int NCHUNK = T_LEN / CHUNK;   // 256
constexpr int BLOCK  = 256;
constexpr int NWAVE  = NCHUNK / 64;     // 4 waves in p2

__device__ __forceinline__ float clamp01(float v) {
    return fminf(fmaxf(v, 0.0f), 1.0f);
}

// ---------------- Phase 1: compose per-chunk affine maps + pack bits ----------------
__global__ __launch_bounds__(BLOCK) void p1_compose(
    const float4* __restrict__ x4, const float* __restrict__ lr_ptr,
    float4* __restrict__ maps, uint4* __restrict__ bitsOut)
{
    const int i  = blockIdx.x * BLOCK + threadIdx.x;   // seq-group
    const int c  = blockIdx.y;                         // chunk
    const int t0 = c * CHUNK;
    const float lr = clamp01(*lr_ptr);

    float obs[4];
    if (c == 0) {
        obs[0]=obs[1]=obs[2]=obs[3]=0.f;
    } else {
        float4 o = x4[(size_t)(t0 - 1) * B4 + i];
        obs[0]=o.x; obs[1]=o.y; obs[2]=o.z; obs[3]=o.w;
    }

    float A0[4]  = {1.f,1.f,1.f,1.f}, Bc0[4] = {0.f,0.f,0.f,0.f};
    float A1[4]  = {1.f,1.f,1.f,1.f}, Bc1[4] = {0.f,0.f,0.f,0.f};
    unsigned bits[4] = {0u,0u,0u,0u};

    #pragma unroll 8
    for (int t = 0; t < CHUNK; ++t) {
        float4 xv = x4[(size_t)(t0 + t) * B4 + i];
        float xt[4] = {xv.x, xv.y, xv.z, xv.w};
        #pragma unroll
        for (int k = 0; k < 4; ++k) {
            bits[k] |= ((unsigned)(xt[k] != 0.0f)) << t;
            float g  = 1.0f - obs[k];          // exact: obs in {0,1}
            float l0 = lr * g;                 // obs=0 -> lr ; obs=1 -> 0
            float l1 = lr - l0;                // exact complement
            float a0 = 1.0f - l0;
            float a1 = 1.0f - l1;
            Bc0[k] = fmaf(a0, Bc0[k], l0 * xt[k]);  A0[k] *= a0;
            Bc1[k] = fmaf(a1, Bc1[k], l1 * xt[k]);  A1[k] *= a1;
            obs[k] = xt[k];
        }
    }

    const size_t base = ((size_t)c * B4 + i) * 4;   // AoS: A0,B0,A1,B1 contiguous
    maps[base + 0] = make_float4(A0[0],  A0[1],  A0[2],  A0[3]);
    maps[base + 1] = make_float4(Bc0[0], Bc0[1], Bc0[2], Bc0[3]);
    maps[base + 2] = make_float4(A1[0],  A1[1],  A1[2],  A1[3]);
    maps[base + 3] = make_float4(Bc1[0], Bc1[1], Bc1[2], Bc1[3]);
    bitsOut[(size_t)c * B4 + i] = make_uint4(bits[0], bits[1], bits[2], bits[3]);
}

// ---------------- Phase 2: parallel scan over chunks ----------------
// One block (NCHUNK=256 threads = 4 waves) per seq-group; thread c holds chunk c's map.
// Intra-wave Kogge-Stone via shuffles; cross-wave combine + exclusive shift via LDS.

__device__ __forceinline__ float4 shfl_up4(float4 v, int d) {
    float4 r;
    r.x = __shfl_up(v.x, d);
    r.y = __shfl_up(v.y, d);
    r.z = __shfl_up(v.z, d);
    r.w = __shfl_up(v.w, d);
    return r;
}

// m := m ∘ p (p applied first):  B = fma(A_self, B_pred, B_self); A = A_self*A_pred
#define COMPOSE4(Aa, Bb, pA, pB)                         \
    Bb.x = fmaf(Aa.x, pB.x, Bb.x);  Aa.x *= pA.x;        \
    Bb.y = fmaf(Aa.y, pB.y, Bb.y);  Aa.y *= pA.y;        \
    Bb.z = fmaf(Aa.z, pB.z, Bb.z);  Aa.z *= pA.z;        \
    Bb.w = fmaf(Aa.w, pB.w, Bb.w);  Aa.w *= pA.w;

__global__ __launch_bounds__(NCHUNK) void p2_scan(
    const float4* __restrict__ maps, float4* __restrict__ sP)
{
    const int i    = blockIdx.x;        // seq-group
    const int c    = threadIdx.x;       // chunk 0..255
    const int lane = c & 63;
    const int wv   = c >> 6;            // wave 0..3

    const size_t base = ((size_t)c * B4 + i) * 4;
    float4 A0 = maps[base + 0], B0 = maps[base + 1];
    float4 A1 = maps[base + 2], B1 = maps[base + 3];

    // intra-wave inclusive scan
    #pragma unroll
    for (int d = 1; d < 64; d <<= 1) {
        float4 pA0 = shfl_up4(A0, d), pB0 = shfl_up4(B0, d);
        float4 pA1 = shfl_up4(A1, d), pB1 = shfl_up4(B1, d);
        if (lane >= d) {
            COMPOSE4(A0, B0, pA0, pB0);
            COMPOSE4(A1, B1, pA1, pB1);
        }
    }

    __shared__ float4 wA0[NWAVE], wB0[NWAVE], wA1[NWAVE], wB1[NWAVE];
    if (lane == 63) { wA0[wv] = A0; wB0[wv] = B0; wA1[wv] = A1; wB1[wv] = B1; }
    __syncthreads();
    // prepend earlier-wave totals, latest-first so the earliest ends up applied first
    for (int w = wv - 1; w >= 0; --w) {
        COMPOSE4(A0, B0, wA0[w], wB0[w]);
        COMPOSE4(A1, B1, wA1[w], wB1[w]);
    }

    __shared__ float4 sA0[NCHUNK], sB0[NCHUNK], sA1[NCHUNK], sB1[NCHUNK];
    sA0[c] = A0; sB0[c] = B0; sA1[c] = A1; sB1[c] = B1;
    __syncthreads();

    float4 eA0, eB0, eA1, eB1;          // exclusive = inclusive of c-1
    if (c == 0) {
        eA0 = make_float4(1,1,1,1); eB0 = make_float4(0,0,0,0);
        eA1 = make_float4(1,1,1,1); eB1 = make_float4(0,0,0,0);
    } else {
        eA0 = sA0[c-1]; eB0 = sB0[c-1];
        eA1 = sA1[c-1]; eB1 = sB1[c-1];
    }
    // chunk-start state = A*0.5 + B   (interleaved: P0 then P1)
    const size_t idx = (size_t)c * B4 + i;
    sP[idx*2 + 0] = make_float4(fmaf(eA0.x, 0.5f, eB0.x), fmaf(eA0.y, 0.5f, eB0.y),
                                fmaf(eA0.z, 0.5f, eB0.z), fmaf(eA0.w, 0.5f, eB0.w));
    sP[idx*2 + 1] = make_float4(fmaf(eA1.x, 0.5f, eB1.x), fmaf(eA1.y, 0.5f, eB1.y),
                                fmaf(eA1.z, 0.5f, eB1.z), fmaf(eA1.w, 0.5f, eB1.w));
}

// ---------------- Phase 3: replay from packed bits, emit predictions ----------------
__global__ __launch_bounds__(BLOCK) void p3_emit(
    const float4* __restrict__ x4, const float* __restrict__ lr_ptr,
    const float4* __restrict__ sP, const uint4* __restrict__ bitsIn,
    float4* __restrict__ out4)
{
    const int i  = blockIdx.x * BLOCK + threadIdx.x;   // seq-group
    const int c  = blockIdx.y;                         // chunk
    const int t0 = c * CHUNK;
    const float lr = clamp01(*lr_ptr);

    const size_t idx = (size_t)c * B4 + i;
    float4 P0 = sP[idx*2 + 0], P1 = sP[idx*2 + 1];
    float p0[4] = {P0.x, P0.y, P0.z, P0.w};
    float p1[4] = {P1.x, P1.y, P1.z, P1.w};

    uint4 bv = bitsIn[idx];
    unsigned w[4] = {bv.x, bv.y, bv.z, bv.w};

    float obs[4];
    if (c == 0) {
        obs[0]=obs[1]=obs[2]=obs[3]=0.f;
    } else {
        float4 o = x4[(size_t)(t0 - 1) * B4 + i];
        obs[0]=o.x; obs[1]=o.y; obs[2]=o.z; obs[3]=o.w;
    }

    #pragma unroll 8
    for (int t = 0; t < CHUNK; ++t) {
        float pr[4];
        #pragma unroll
        for (int k = 0; k < 4; ++k) {
            unsigned bit = (w[k] >> t) & 1u;
            float xf = (float)bit;                 // exact 0.0 / 1.0
            float g  = 1.0f - obs[k];
            float l0 = lr * g;
            float l1 = lr - l0;
            p0[k] = fmaf(l0, xf - p0[k], p0[k]);
            p1[k] = fmaf(l1, xf - p1[k], p1[k]);
            pr[k] = bit ? p1[k] : p0[k];           // exact select, matches ref
            obs[k] = xf;
        }
        out4[(size_t)(t0 + t) * B4 + i] = make_float4(pr[0], pr[1], pr[2], pr[3]);
    }
}

extern "C" void kernel_launch(void* const* d_in, const int* in_sizes, int n_in,
                              void* d_out, int out_size, void* d_ws, size_t ws_size,
                              hipStream_t stream) {
    const float4* x4  = (const float4*)d_in[0];
    const float*  lr  = (const float*)d_in[1];
    float4*       out = (float4*)d_out;

    // Workspace: maps (AoS, 4n float4 = 16 MiB) + sP (2n float4 = 8 MiB)
    //          + bits (n uint4 = 4 MiB) = 28 MiB
    const size_t n = (size_t)NCHUNK * B4;   // 262144
    float4* maps = (float4*)d_ws;
    float4* sP   = maps + 4 * n;
    uint4*  bits = (uint4*)(sP + 2 * n);

    dim3 grid13(B4 / BLOCK, NCHUNK);   // 4 x 256 = 1024 blocks
    p1_compose<<<grid13, BLOCK, 0, stream>>>(x4, lr, maps, bits);
    p2_scan<<<dim3(B4), NCHUNK, 0, stream>>>(maps, sP);
    p3_emit<<<grid13, BLOCK, 0, stream>>>(x4, lr, sP, bits, out);
}